// Round 18
// baseline (161.958 us; speedup 1.0000x reference)
//
#include <hip/hip_runtime.h>
#include <stdint.h>

// ---------------------------------------------------------------------------
// Fused MHA block: qkv proj -> flash attention -> out proj.
// Inputs fp32, output fp32; bf16 MFMA compute, fp32 accum.
// B=4 N=2048 C=512 H=8 D=64 fixed.
// R18: split-KV attention (2 blocks per q-tile, 8 iters each; static-max
// softmax makes partials associative: O_num and l just add). fp32 partials
// in ws + tiny combine kernel. Rest identical to R17.
// ---------------------------------------------------------------------------

typedef short bf16x8 __attribute__((ext_vector_type(8)));   // 8 bf16 = 4 VGPRs
typedef float f32x2  __attribute__((ext_vector_type(2)));
typedef float f32x4  __attribute__((ext_vector_type(4)));
typedef float f32x16 __attribute__((ext_vector_type(16)));
typedef unsigned int u32x4 __attribute__((ext_vector_type(4)));

__device__ __forceinline__ unsigned short f2bf(float f) {
    unsigned int u = __builtin_bit_cast(unsigned int, f);
    u += 0x7fffu + ((u >> 16) & 1u);
    return (unsigned short)(u >> 16);
}
__device__ __forceinline__ unsigned int pk2(float a, float b) {
    return (unsigned int)f2bf(a) | ((unsigned int)f2bf(b) << 16);
}
__device__ __forceinline__ float fexp2(float x) {
    return __builtin_amdgcn_exp2f(x);    // bare v_exp_f32
}
__device__ __forceinline__ bf16x8 ld8_f32(const float* __restrict__ p) {
    float4 f0 = *(const float4*)p;
    float4 f1 = *(const float4*)(p + 4);
    u32x4 u = {pk2(f0.x, f0.y), pk2(f0.z, f0.w), pk2(f1.x, f1.y), pk2(f1.z, f1.w)};
    return __builtin_bit_cast(bf16x8, u);
}
__device__ __forceinline__ void async16(const void* g, void* l) {
    __builtin_amdgcn_global_load_lds(
        (const __attribute__((address_space(1))) unsigned int*)g,
        (__attribute__((address_space(3))) unsigned int*)l,
        16, 0, 0);
}

#define MFMA16(a, b, c) __builtin_amdgcn_mfma_f32_16x16x32_bf16((a), (b), (c), 0, 0, 0)
#define MFMA32(a, b, c) __builtin_amdgcn_mfma_f32_32x32x16_bf16((a), (b), (c), 0, 0, 0)

// ---------------------------------------------------------------------------
// fp32 -> bf16 bulk convert: x, qkv_w, proj_w in one pass.
// ---------------------------------------------------------------------------
__global__ void cvt_bf16(const float* __restrict__ x,
                         const float* __restrict__ w,
                         const float* __restrict__ w2,
                         unsigned short* __restrict__ xb,
                         unsigned short* __restrict__ wb,
                         unsigned short* __restrict__ wb2)
{
    const int G = 524288 + 98304 + 32768;
    for (int idx = blockIdx.x * 256 + threadIdx.x; idx < G; idx += gridDim.x * 256) {
        if (idx < 524288)
            *(bf16x8*)(xb + (size_t)idx * 8) = ld8_f32(x + (size_t)idx * 8);
        else if (idx < 524288 + 98304) {
            int j = idx - 524288;
            *(bf16x8*)(wb + (size_t)j * 8) = ld8_f32(w + (size_t)j * 8);
        } else {
            int j = idx - 524288 - 98304;
            *(bf16x8*)(wb2 + (size_t)j * 8) = ld8_f32(w2 + (size_t)j * 8);
        }
    }
}

// ---------------------------------------------------------------------------
// QKV GEMM (unchanged from R17): 128x128 tile, BK=32, dual DMA, XCD remap.
// ---------------------------------------------------------------------------
__global__ __launch_bounds__(256, 4)
void gemm_qkv(const unsigned short* __restrict__ A,
              const unsigned short* __restrict__ B,
              const float* __restrict__ bias,
              unsigned short* __restrict__ out0,
              unsigned short* __restrict__ out1,
              unsigned short* __restrict__ out2,
              int K)
{
    __shared__ unsigned short sA[128 * 32];
    __shared__ unsigned short sB[128 * 32];

    const int tid  = threadIdx.x;
    const int wave = tid >> 6, lane = tid & 63;
    const int l = lane & 15, q16 = lane >> 4;
    const int wm = wave >> 1, wn = wave & 1;
    const int bid = blockIdx.x;                  // 0..767
    const int slot = bid >> 3;                   // 0..95
    const int m0 = ((bid & 7) * 8 + slot / 12) * 128;
    const int n0 = (slot % 12) * 128;

    f32x4 acc[4][4];
#pragma unroll
    for (int i = 0; i < 4; ++i)
#pragma unroll
        for (int j = 0; j < 4; ++j)
            acc[i][j] = (f32x4){0.f, 0.f, 0.f, 0.f};

    for (int k0 = 0; k0 < K; k0 += 32) {
#pragma unroll
        for (int call = 0; call < 2; ++call) {
            int L = call * 256 + tid;
            int r = L >> 2, c = L & 3;
            async16(A + (size_t)(m0 + r) * K + k0 + c * 8, sA + L * 8);
            async16(B + (size_t)(n0 + r) * K + k0 + c * 8, sB + L * 8);
        }
        __syncthreads();

        bf16x8 af[4], bfr[4];
#pragma unroll
        for (int i = 0; i < 4; ++i)
            af[i] = *(const bf16x8*)(sA + ((wm * 64 + i * 16 + l) * 4 + q16) * 8);
#pragma unroll
        for (int j = 0; j < 4; ++j)
            bfr[j] = *(const bf16x8*)(sB + ((wn * 64 + j * 16 + l) * 4 + q16) * 8);
#pragma unroll
        for (int i = 0; i < 4; ++i)
#pragma unroll
            for (int j = 0; j < 4; ++j)
                acc[i][j] = MFMA16(af[i], bfr[j], acc[i][j]);
        __syncthreads();
    }

    const float lscale = 0.18033688f;  // D^-0.5 * log2(e), folded into q
#pragma unroll
    for (int i = 0; i < 4; ++i) {
#pragma unroll
        for (int j = 0; j < 4; ++j) {
            int col = n0 + wn * 64 + j * 16 + l;
            float bv = bias[col];
#pragma unroll
            for (int r = 0; r < 4; ++r) {
                int row = m0 + wm * 64 + i * 16 + q16 * 4 + r;
                float val = acc[i][j][r] + bv;
                int which = col >> 9;            // 0:q 1:k 2:v
                int h = (col >> 6) & 7, d = col & 63;
                int b = row >> 11, n = row & 2047;
                if (which == 0)
                    out0[(size_t)(((b * 8 + h) * 2048) + n) * 64 + d] = f2bf(val * lscale);
                else if (which == 1)
                    out1[(size_t)(((b * 8 + h) * 2048) + n) * 64 + d] = f2bf(val);
                else {
                    // V^T with pi(n): swap bits 2<->3 of n (within 32-blocks)
                    int np = (n & ~12) | ((n & 8) >> 1) | ((n & 4) << 1);
                    out2[(size_t)(((b * 8 + h) * 64) + d) * 2048 + np] = f2bf(val);
                }
            }
        }
    }
}

// ---------------------------------------------------------------------------
// Output GEMM (unchanged from R17).
// ---------------------------------------------------------------------------
__global__ __launch_bounds__(256, 4)
void gemm_out(const unsigned short* __restrict__ A,
              const unsigned short* __restrict__ B,
              const float* __restrict__ bias,
              float* __restrict__ outf,
              int K, int N)
{
    __shared__ unsigned short sA[64 * 32];
    __shared__ unsigned short sB[128 * 32];

    const int tid  = threadIdx.x;
    const int wave = tid >> 6, lane = tid & 63;
    const int l = lane & 15, q16 = lane >> 4;
    const int wm = wave >> 1, wn = wave & 1;
    const int bid = blockIdx.x;                  // 0..511
    const int slot = bid >> 3;                   // 0..63
    const int m0 = ((bid & 7) * 16 + (slot >> 2)) * 64;
    const int n0 = (slot & 3) * 128;

    f32x4 acc[2][4];
#pragma unroll
    for (int i = 0; i < 2; ++i)
#pragma unroll
        for (int j = 0; j < 4; ++j)
            acc[i][j] = (f32x4){0.f, 0.f, 0.f, 0.f};

    for (int k0 = 0; k0 < K; k0 += 32) {
        {
            int r = tid >> 2, c = tid & 3;       // A: 256 slots
            async16(A + (size_t)(m0 + r) * K + k0 + c * 8, sA + tid * 8);
        }
#pragma unroll
        for (int call = 0; call < 2; ++call) {   // B: 512 slots
            int L = call * 256 + tid;
            int r = L >> 2, c = L & 3;
            async16(B + (size_t)(n0 + r) * K + k0 + c * 8, sB + L * 8);
        }
        __syncthreads();

        bf16x8 af[2], bfr[4];
#pragma unroll
        for (int i = 0; i < 2; ++i)
            af[i] = *(const bf16x8*)(sA + ((wm * 32 + i * 16 + l) * 4 + q16) * 8);
#pragma unroll
        for (int j = 0; j < 4; ++j)
            bfr[j] = *(const bf16x8*)(sB + ((wn * 64 + j * 16 + l) * 4 + q16) * 8);
#pragma unroll
        for (int i = 0; i < 2; ++i)
#pragma unroll
            for (int j = 0; j < 4; ++j)
                acc[i][j] = MFMA16(af[i], bfr[j], acc[i][j]);
        __syncthreads();
    }

#pragma unroll
    for (int i = 0; i < 2; ++i) {
#pragma unroll
        for (int j = 0; j < 4; ++j) {
            int col = n0 + wn * 64 + j * 16 + l;
            float bv = bias[col];
#pragma unroll
            for (int r = 0; r < 4; ++r) {
                int row = m0 + wm * 32 + i * 16 + q16 * 4 + r;
                outf[(size_t)row * N + col] = acc[i][j][r] + bv;
            }
        }
    }
}

// ---------------------------------------------------------------------------
// Flash attention, split-KV: 2 blocks per (bh, q-tile), each covers 1024 kv
// (8 iters). Static-max softmax => partials associative (O_num, l add).
// Writes fp32 O^T numerator + l partial to ws. Grid 1024 (4 blocks/CU).
// XCD remap: 4 heads/XCD, both parts of a q-tile on the same XCD.
// ---------------------------------------------------------------------------
__global__ __launch_bounds__(256, 2)
void attn_fused(const unsigned short* __restrict__ Q,
                const unsigned short* __restrict__ Km,
                const unsigned short* __restrict__ Vt,
                float* __restrict__ pO,
                float* __restrict__ pl)
{
    __shared__ unsigned short sK[2][128 * 64];
    __shared__ unsigned short sVt[2][64 * 128];

    const int tid  = threadIdx.x;
    const int wave = tid >> 6, lane = tid & 63;
    const int l31 = lane & 31, h = lane >> 5;
    const int swz = l31 & 7;
    const int bid = blockIdx.x;                  // 0..1023
    const int slot = bid >> 3;                   // 0..127
    const int bh = (bid & 7) * 4 + (slot >> 5);  // 4 heads per XCD
    const int rest = slot & 31;
    const int n0 = (rest >> 1) * 128;            // q tile
    const int part = rest & 1;                   // KV half
    const int q0 = n0 + wave * 32;

    const unsigned short* Kp = Km + (size_t)bh * 2048 * 64 + (size_t)part * 1024 * 64;
    const unsigned short* Vp = Vt + (size_t)bh * 64 * 2048 + (size_t)part * 1024;
    const unsigned short* sKf = &sK[0][0];
    const unsigned short* sVf = &sVt[0][0];

    int ka[4], va[2][2];
#pragma unroll
    for (int ks = 0; ks < 4; ++ks)
        ka[ks] = l31 * 64 + ((ks * 2 + h) ^ swz) * 8;
#pragma unroll
    for (int m1 = 0; m1 < 2; ++m1)
#pragma unroll
        for (int ks2 = 0; ks2 < 2; ++ks2)
            va[m1][ks2] = l31 * 128 + ((m1 * 4 + ks2 * 2 + h) ^ swz) * 8;

    int ksrc[4], vsrc[4], dst[4];
#pragma unroll
    for (int c = 0; c < 4; ++c) {
        int s = wave * 256 + c * 64 + lane;
        int rk = s >> 3;
        ksrc[c] = rk * 64 + ((s & 7) ^ (rk & 7)) * 8;
        int rv = s >> 4;
        vsrc[c] = rv * 2048 + ((s & 15) ^ (rv & 7)) * 8;
        dst[c] = s * 8;
    }

    bf16x8 qf[4];
#pragma unroll
    for (int ks = 0; ks < 4; ++ks)
        qf[ks] = *(const bf16x8*)(Q + (size_t)(bh * 2048 + q0 + l31) * 64 + ks * 16 + h * 8);

    f32x16 oacc[2];
#pragma unroll
    for (int dt = 0; dt < 2; ++dt)
#pragma unroll
        for (int e = 0; e < 16; ++e) oacc[dt][e] = 0.f;
    f32x16 Zv;
#pragma unroll
    for (int e = 0; e < 16; ++e) Zv[e] = 0.f;
    f32x2 l2 = {0.f, 0.f};

#pragma unroll
    for (int c = 0; c < 4; ++c) {
        async16(Kp + ksrc[c], (void*)(sKf + dst[c]));
        async16(Vp + vsrc[c], (void*)(sVf + dst[c]));
    }
    __syncthreads();

    for (int it = 0; it < 8; ++it) {
        const int nb = ((it + 1) & 1) * 8192;
        if (it < 7) {
            int kv = (it + 1) * 128;
#pragma unroll
            for (int c = 0; c < 4; ++c)
                async16(Kp + (size_t)kv * 64 + ksrc[c], (void*)(sKf + nb + dst[c]));
        }

        f32x16 sacc[4];
#pragma unroll
        for (int mt = 0; mt < 4; ++mt) {
            bf16x8 kf0 = *(const bf16x8*)(sKf + ka[0] + mt * 2048);
            sacc[mt] = MFMA32(kf0, qf[0], Zv);
#pragma unroll
            for (int ks = 1; ks < 4; ++ks) {
                bf16x8 kf = *(const bf16x8*)(sKf + ka[ks] + mt * 2048);
                sacc[mt] = MFMA32(kf, qf[ks], sacc[mt]);
            }
        }

        if (it < 7) {
            int kv = (it + 1) * 128;
#pragma unroll
            for (int c = 0; c < 4; ++c)
                async16(Vp + (size_t)kv + vsrc[c], (void*)(sVf + nb + dst[c]));
        }

        unsigned int pk[4][4][2];
#pragma unroll
        for (int mt = 0; mt < 4; ++mt)
#pragma unroll
            for (int g = 0; g < 4; ++g) {
                float p0 = fexp2(sacc[mt][4 * g + 0]);
                float p1 = fexp2(sacc[mt][4 * g + 1]);
                float p2 = fexp2(sacc[mt][4 * g + 2]);
                float p3 = fexp2(sacc[mt][4 * g + 3]);
                l2 += (f32x2){p0, p1};
                l2 += (f32x2){p2, p3};
                pk[mt][g][0] = __builtin_amdgcn_perm(
                    __builtin_bit_cast(unsigned int, p1),
                    __builtin_bit_cast(unsigned int, p0), 0x07060302u);
                pk[mt][g][1] = __builtin_amdgcn_perm(
                    __builtin_bit_cast(unsigned int, p3),
                    __builtin_bit_cast(unsigned int, p2), 0x07060302u);
            }

#pragma unroll
        for (int mt = 0; mt < 4; ++mt) {
#pragma unroll
            for (int ks2 = 0; ks2 < 2; ++ks2) {
                u32x4 bu;
                bu[0] = pk[mt][2 * ks2][0];
                bu[1] = pk[mt][2 * ks2][1];
                bu[2] = pk[mt][2 * ks2 + 1][0];
                bu[3] = pk[mt][2 * ks2 + 1][1];
                bf16x8 bfrag = __builtin_bit_cast(bf16x8, bu);
#pragma unroll
                for (int dt = 0; dt < 2; ++dt) {
                    bf16x8 vf = *(const bf16x8*)(sVf + va[mt & 1][ks2]
                                                 + (mt >> 1) * 64 + dt * 4096);
                    oacc[dt] = MFMA32(vf, bfrag, oacc[dt]);
                }
            }
        }

#pragma unroll
        for (int ks = 0; ks < 4; ++ks) ka[ks] ^= 8192;
        va[0][0] ^= 8192; va[0][1] ^= 8192; va[1][0] ^= 8192; va[1][1] ^= 8192;
        __syncthreads();
    }

    // epilogue: write fp32 O^T numerator partial + l partial (no divide)
    float l_run = l2[0] + l2[1];
    l_run += __shfl_xor(l_run, 32);
    float* pOb = pO + (((size_t)(part * 32 + bh)) * 2048 + (q0 + l31)) * 64;
#pragma unroll
    for (int dt = 0; dt < 2; ++dt)
#pragma unroll
        for (int g = 0; g < 4; ++g) {
            int d = dt * 32 + 8 * g + 4 * h;
            float4 v = {oacc[dt][4 * g + 0], oacc[dt][4 * g + 1],
                        oacc[dt][4 * g + 2], oacc[dt][4 * g + 3]};
            *(float4*)(pOb + d) = v;
        }
    if (h == 0)
        pl[((size_t)(part * 32 + bh)) * 2048 + (q0 + l31)] = l_run;
}

// ---------------------------------------------------------------------------
// Combine: O = (O_part0 + O_part1) / (l0 + l1), write bf16 [b][q][hh*64+d].
// 1,048,576 threads, one float4 (4 d) each.
// ---------------------------------------------------------------------------
__global__ void attn_combine(const float* __restrict__ pO,
                             const float* __restrict__ pl,
                             unsigned short* __restrict__ O)
{
    int idx = blockIdx.x * 256 + threadIdx.x;    // 0..1048575
    int d4 = (idx & 15) * 4;
    int q  = (idx >> 4) & 2047;
    int bh = idx >> 15;                          // 0..31
    size_t o0 = (((size_t)bh) * 2048 + q) * 64 + d4;
    size_t o1 = (((size_t)(32 + bh)) * 2048 + q) * 64 + d4;
    float4 a = *(const float4*)(pO + o0);
    float4 b = *(const float4*)(pO + o1);
    float l = pl[(size_t)bh * 2048 + q] + pl[(size_t)(32 + bh) * 2048 + q];
    float inv = 1.f / fmaxf(l, 1e-20f);
    int bb = bh >> 3, hh = bh & 7;
    unsigned short* out = O + (((size_t)(bb * 2048 + q)) * 512 + hh * 64 + d4);
    unsigned int w0 = pk2((a.x + b.x) * inv, (a.y + b.y) * inv);
    unsigned int w1 = pk2((a.z + b.z) * inv, (a.w + b.w) * inv);
    uint2 w = {w0, w1};
    *(uint2*)out = w;
}

// ---------------------------------------------------------------------------
extern "C" void kernel_launch(void* const* d_in, const int* in_sizes, int n_in,
                              void* d_out, int out_size, void* d_ws, size_t ws_size,
                              hipStream_t stream)
{
    const float* x      = (const float*)d_in[0];  // [4,2048,512]
    const float* qkv_w  = (const float*)d_in[1];  // [1536,512]
    const float* qkv_b  = (const float*)d_in[2];  // [1536]
    const float* proj_w = (const float*)d_in[3];  // [512,512]
    const float* proj_b = (const float*)d_in[4];  // [512]

    const size_t PER = 4u * 8u * 2048u * 64u;     // 4,194,304 elems (8 MB bf16)
    unsigned short* q_ws  = (unsigned short*)d_ws;
    unsigned short* k_ws  = q_ws  + PER;
    unsigned short* vt_ws = k_ws  + PER;
    unsigned short* ao_ws = vt_ws + PER;
    unsigned short* wb2   = ao_ws + PER;          // proj_w bf16 (0.5 MB)
    float* pO = (float*)(wb2 + 262144);           // 2 x 32 x 2048 x 64 fp32 (64 MB)
    float* pl = pO + (size_t)2 * 32 * 2048 * 64;  // 2 x 32 x 2048 fp32 (0.5 MB)

    // bf16 scratch inside d_out (16 MB; dead until final GEMM overwrites it)
    unsigned short* xb = (unsigned short*)d_out;          // 8 MB
    unsigned short* wb = xb + PER;                        // 1.5 MB

    // 0) bulk fp32->bf16 of x, qkv_w, proj_w (one launch)
    cvt_bf16<<<dim3(640), 256, 0, stream>>>(x, qkv_w, proj_w, xb, wb, wb2);
    // 1) QKV projection: M=8192, N=1536, K=512 (XCD-remapped)
    gemm_qkv<<<dim3(768), 256, 0, stream>>>(xb, wb, qkv_b, q_ws, k_ws, vt_ws, 512);
    // 2) Flash attention, split-KV: 1024 blocks (4/CU), partials to ws
    attn_fused<<<dim3(1024), 256, 0, stream>>>(q_ws, k_ws, vt_ws, pO, pl);
    // 2b) combine partials -> ao_ws
    attn_combine<<<dim3(4096), 256, 0, stream>>>(pO, pl, ao_ws);
    // 3) Output projection: M=8192, N=512, K=512 (XCD-remapped)
    gemm_out<<<dim3(512), 256, 0, stream>>>(ao_ws, wb2, proj_b, (float*)d_out, 512, 512);
}

// Round 19
// 155.147 us; speedup vs baseline: 1.0439x; 1.0439x over previous
//
#include <hip/hip_runtime.h>
#include <stdint.h>

// ---------------------------------------------------------------------------
// Fused MHA block: qkv proj -> flash attention -> out proj.
// Inputs fp32, output fp32; bf16 MFMA compute, fp32 accum.
// B=4 N=2048 C=512 H=8 D=64 fixed.
// R19: R17 + fixed attn LDS swizzle c^(r&7)^((r>>3)&3) -- kills the 4-way
// bank conflict on every ds_read_b128 (4.19M conflict cycles/dispatch).
// ---------------------------------------------------------------------------

typedef short bf16x8 __attribute__((ext_vector_type(8)));   // 8 bf16 = 4 VGPRs
typedef float f32x2  __attribute__((ext_vector_type(2)));
typedef float f32x4  __attribute__((ext_vector_type(4)));
typedef float f32x16 __attribute__((ext_vector_type(16)));
typedef unsigned int u32x4 __attribute__((ext_vector_type(4)));

__device__ __forceinline__ unsigned short f2bf(float f) {
    unsigned int u = __builtin_bit_cast(unsigned int, f);
    u += 0x7fffu + ((u >> 16) & 1u);
    return (unsigned short)(u >> 16);
}
__device__ __forceinline__ unsigned int pk2(float a, float b) {
    return (unsigned int)f2bf(a) | ((unsigned int)f2bf(b) << 16);
}
__device__ __forceinline__ float fexp2(float x) {
    return __builtin_amdgcn_exp2f(x);    // bare v_exp_f32
}
__device__ __forceinline__ bf16x8 ld8_f32(const float* __restrict__ p) {
    float4 f0 = *(const float4*)p;
    float4 f1 = *(const float4*)(p + 4);
    u32x4 u = {pk2(f0.x, f0.y), pk2(f0.z, f0.w), pk2(f1.x, f1.y), pk2(f1.z, f1.w)};
    return __builtin_bit_cast(bf16x8, u);
}
__device__ __forceinline__ void async16(const void* g, void* l) {
    __builtin_amdgcn_global_load_lds(
        (const __attribute__((address_space(1))) unsigned int*)g,
        (__attribute__((address_space(3))) unsigned int*)l,
        16, 0, 0);
}

#define MFMA16(a, b, c) __builtin_amdgcn_mfma_f32_16x16x32_bf16((a), (b), (c), 0, 0, 0)
#define MFMA32(a, b, c) __builtin_amdgcn_mfma_f32_32x32x16_bf16((a), (b), (c), 0, 0, 0)

// ---------------------------------------------------------------------------
// fp32 -> bf16 bulk convert: x, qkv_w, proj_w in one pass.
// ---------------------------------------------------------------------------
__global__ void cvt_bf16(const float* __restrict__ x,
                         const float* __restrict__ w,
                         const float* __restrict__ w2,
                         unsigned short* __restrict__ xb,
                         unsigned short* __restrict__ wb,
                         unsigned short* __restrict__ wb2)
{
    const int G = 524288 + 98304 + 32768;
    for (int idx = blockIdx.x * 256 + threadIdx.x; idx < G; idx += gridDim.x * 256) {
        if (idx < 524288)
            *(bf16x8*)(xb + (size_t)idx * 8) = ld8_f32(x + (size_t)idx * 8);
        else if (idx < 524288 + 98304) {
            int j = idx - 524288;
            *(bf16x8*)(wb + (size_t)j * 8) = ld8_f32(w + (size_t)j * 8);
        } else {
            int j = idx - 524288 - 98304;
            *(bf16x8*)(wb2 + (size_t)j * 8) = ld8_f32(w2 + (size_t)j * 8);
        }
    }
}

// ---------------------------------------------------------------------------
// QKV GEMM (unchanged from R17): 128x128 tile, BK=32, dual DMA, XCD remap.
// ---------------------------------------------------------------------------
__global__ __launch_bounds__(256, 4)
void gemm_qkv(const unsigned short* __restrict__ A,
              const unsigned short* __restrict__ B,
              const float* __restrict__ bias,
              unsigned short* __restrict__ out0,
              unsigned short* __restrict__ out1,
              unsigned short* __restrict__ out2,
              int K)
{
    __shared__ unsigned short sA[128 * 32];
    __shared__ unsigned short sB[128 * 32];

    const int tid  = threadIdx.x;
    const int wave = tid >> 6, lane = tid & 63;
    const int l = lane & 15, q16 = lane >> 4;
    const int wm = wave >> 1, wn = wave & 1;
    const int bid = blockIdx.x;                  // 0..767
    const int slot = bid >> 3;                   // 0..95
    const int m0 = ((bid & 7) * 8 + slot / 12) * 128;
    const int n0 = (slot % 12) * 128;

    f32x4 acc[4][4];
#pragma unroll
    for (int i = 0; i < 4; ++i)
#pragma unroll
        for (int j = 0; j < 4; ++j)
            acc[i][j] = (f32x4){0.f, 0.f, 0.f, 0.f};

    for (int k0 = 0; k0 < K; k0 += 32) {
#pragma unroll
        for (int call = 0; call < 2; ++call) {
            int L = call * 256 + tid;
            int r = L >> 2, c = L & 3;
            async16(A + (size_t)(m0 + r) * K + k0 + c * 8, sA + L * 8);
            async16(B + (size_t)(n0 + r) * K + k0 + c * 8, sB + L * 8);
        }
        __syncthreads();

        bf16x8 af[4], bfr[4];
#pragma unroll
        for (int i = 0; i < 4; ++i)
            af[i] = *(const bf16x8*)(sA + ((wm * 64 + i * 16 + l) * 4 + q16) * 8);
#pragma unroll
        for (int j = 0; j < 4; ++j)
            bfr[j] = *(const bf16x8*)(sB + ((wn * 64 + j * 16 + l) * 4 + q16) * 8);
#pragma unroll
        for (int i = 0; i < 4; ++i)
#pragma unroll
            for (int j = 0; j < 4; ++j)
                acc[i][j] = MFMA16(af[i], bfr[j], acc[i][j]);
        __syncthreads();
    }

    const float lscale = 0.18033688f;  // D^-0.5 * log2(e), folded into q
#pragma unroll
    for (int i = 0; i < 4; ++i) {
#pragma unroll
        for (int j = 0; j < 4; ++j) {
            int col = n0 + wn * 64 + j * 16 + l;
            float bv = bias[col];
#pragma unroll
            for (int r = 0; r < 4; ++r) {
                int row = m0 + wm * 64 + i * 16 + q16 * 4 + r;
                float val = acc[i][j][r] + bv;
                int which = col >> 9;            // 0:q 1:k 2:v
                int h = (col >> 6) & 7, d = col & 63;
                int b = row >> 11, n = row & 2047;
                if (which == 0)
                    out0[(size_t)(((b * 8 + h) * 2048) + n) * 64 + d] = f2bf(val * lscale);
                else if (which == 1)
                    out1[(size_t)(((b * 8 + h) * 2048) + n) * 64 + d] = f2bf(val);
                else {
                    // V^T with pi(n): swap bits 2<->3 of n (within 32-blocks)
                    int np = (n & ~12) | ((n & 8) >> 1) | ((n & 4) << 1);
                    out2[(size_t)(((b * 8 + h) * 64) + d) * 2048 + np] = f2bf(val);
                }
            }
        }
    }
}

// ---------------------------------------------------------------------------
// Output GEMM (unchanged from R17).
// ---------------------------------------------------------------------------
__global__ __launch_bounds__(256, 4)
void gemm_out(const unsigned short* __restrict__ A,
              const unsigned short* __restrict__ B,
              const float* __restrict__ bias,
              float* __restrict__ outf,
              int K, int N)
{
    __shared__ unsigned short sA[64 * 32];
    __shared__ unsigned short sB[128 * 32];

    const int tid  = threadIdx.x;
    const int wave = tid >> 6, lane = tid & 63;
    const int l = lane & 15, q16 = lane >> 4;
    const int wm = wave >> 1, wn = wave & 1;
    const int bid = blockIdx.x;                  // 0..511
    const int slot = bid >> 3;                   // 0..63
    const int m0 = ((bid & 7) * 16 + (slot >> 2)) * 64;
    const int n0 = (slot & 3) * 128;

    f32x4 acc[2][4];
#pragma unroll
    for (int i = 0; i < 2; ++i)
#pragma unroll
        for (int j = 0; j < 4; ++j)
            acc[i][j] = (f32x4){0.f, 0.f, 0.f, 0.f};

    for (int k0 = 0; k0 < K; k0 += 32) {
        {
            int r = tid >> 2, c = tid & 3;       // A: 256 slots
            async16(A + (size_t)(m0 + r) * K + k0 + c * 8, sA + tid * 8);
        }
#pragma unroll
        for (int call = 0; call < 2; ++call) {   // B: 512 slots
            int L = call * 256 + tid;
            int r = L >> 2, c = L & 3;
            async16(B + (size_t)(n0 + r) * K + k0 + c * 8, sB + L * 8);
        }
        __syncthreads();

        bf16x8 af[2], bfr[4];
#pragma unroll
        for (int i = 0; i < 2; ++i)
            af[i] = *(const bf16x8*)(sA + ((wm * 32 + i * 16 + l) * 4 + q16) * 8);
#pragma unroll
        for (int j = 0; j < 4; ++j)
            bfr[j] = *(const bf16x8*)(sB + ((wn * 64 + j * 16 + l) * 4 + q16) * 8);
#pragma unroll
        for (int i = 0; i < 2; ++i)
#pragma unroll
            for (int j = 0; j < 4; ++j)
                acc[i][j] = MFMA16(af[i], bfr[j], acc[i][j]);
        __syncthreads();
    }

#pragma unroll
    for (int i = 0; i < 2; ++i) {
#pragma unroll
        for (int j = 0; j < 4; ++j) {
            int col = n0 + wn * 64 + j * 16 + l;
            float bv = bias[col];
#pragma unroll
            for (int r = 0; r < 4; ++r) {
                int row = m0 + wm * 32 + i * 16 + q16 * 4 + r;
                outf[(size_t)row * N + col] = acc[i][j][r] + bv;
            }
        }
    }
}

// ---------------------------------------------------------------------------
// Flash attention (R17/R14 structure): 256 threads, double-buffered DMA
// staging, S^T on 32x32x16, static-max softmax, swap-free PV via pi-permuted
// V^T. XCD remap: 4 heads/XCD. NEW: full-rank LDS swizzle c^(r&7)^((r>>3)&3)
// -> ds_read_b128 conflict-free (was 4-way: lanes {x,x+8,x+16,x+24} shared
// the granule column under the old c^(r&7)).
// ---------------------------------------------------------------------------
__global__ __launch_bounds__(256, 2)
void attn_fused(const unsigned short* __restrict__ Q,
                const unsigned short* __restrict__ Km,
                const unsigned short* __restrict__ Vt,
                unsigned short* __restrict__ O)
{
    __shared__ unsigned short sK[2][128 * 64];
    __shared__ unsigned short sVt[2][64 * 128];

    const int tid  = threadIdx.x;
    const int wave = tid >> 6, lane = tid & 63;
    const int l31 = lane & 31, h = lane >> 5;
    const int swz = (l31 & 7) ^ ((l31 >> 3) & 3);   // full-rank row swizzle
    const int bid = blockIdx.x;                  // 0..511
    const int slot = bid >> 3;                   // 0..63
    const int bh = (bid & 7) * 4 + (slot >> 4);  // 4 heads per XCD
    const int n0 = (slot & 15) * 128;
    const int q0 = n0 + wave * 32;

    const unsigned short* Kp = Km + (size_t)bh * 2048 * 64;
    const unsigned short* Vp = Vt + (size_t)bh * 64 * 2048;
    const unsigned short* sKf = &sK[0][0];
    const unsigned short* sVf = &sVt[0][0];

    // hoisted LDS read offsets; rows rk=mt*32+l31 / rv=dt*32+l31 share swz
    int ka[4], va[2][2];
#pragma unroll
    for (int ks = 0; ks < 4; ++ks)
        ka[ks] = l31 * 64 + ((ks * 2 + h) ^ swz) * 8;
#pragma unroll
    for (int m1 = 0; m1 < 2; ++m1)
#pragma unroll
        for (int ks2 = 0; ks2 < 2; ++ks2)
            va[m1][ks2] = l31 * 128 + ((m1 * 4 + ks2 * 2 + h) ^ swz) * 8;

    // hoisted DMA offsets (dst linear per slot; source granule swizzled)
    int ksrc[4], vsrc[4], dst[4];
#pragma unroll
    for (int c = 0; c < 4; ++c) {
        int s = wave * 256 + c * 64 + lane;
        int rk = s >> 3;
        ksrc[c] = rk * 64 + (((s & 7) ^ (rk & 7) ^ ((rk >> 3) & 3)) * 8);
        int rv = s >> 4;
        vsrc[c] = rv * 2048 + (((s & 15) ^ (rv & 7) ^ ((rv >> 3) & 3)) * 8);
        dst[c] = s * 8;
    }

    bf16x8 qf[4];
#pragma unroll
    for (int ks = 0; ks < 4; ++ks)
        qf[ks] = *(const bf16x8*)(Q + (size_t)(bh * 2048 + q0 + l31) * 64 + ks * 16 + h * 8);

    f32x16 oacc[2];
#pragma unroll
    for (int dt = 0; dt < 2; ++dt)
#pragma unroll
        for (int e = 0; e < 16; ++e) oacc[dt][e] = 0.f;
    f32x16 Zv;
#pragma unroll
    for (int e = 0; e < 16; ++e) Zv[e] = 0.f;
    f32x2 l2 = {0.f, 0.f};

#pragma unroll
    for (int c = 0; c < 4; ++c) {
        async16(Kp + ksrc[c], (void*)(sKf + dst[c]));
        async16(Vp + vsrc[c], (void*)(sVf + dst[c]));
    }
    __syncthreads();

    for (int it = 0; it < 16; ++it) {
        const int nb = ((it + 1) & 1) * 8192;
        if (it < 15) {
            int kv = (it + 1) * 128;
#pragma unroll
            for (int c = 0; c < 4; ++c)
                async16(Kp + (size_t)kv * 64 + ksrc[c], (void*)(sKf + nb + dst[c]));
        }

        f32x16 sacc[4];
#pragma unroll
        for (int mt = 0; mt < 4; ++mt) {
            bf16x8 kf0 = *(const bf16x8*)(sKf + ka[0] + mt * 2048);
            sacc[mt] = MFMA32(kf0, qf[0], Zv);
#pragma unroll
            for (int ks = 1; ks < 4; ++ks) {
                bf16x8 kf = *(const bf16x8*)(sKf + ka[ks] + mt * 2048);
                sacc[mt] = MFMA32(kf, qf[ks], sacc[mt]);
            }
        }

        if (it < 15) {
            int kv = (it + 1) * 128;
#pragma unroll
            for (int c = 0; c < 4; ++c)
                async16(Vp + (size_t)kv + vsrc[c], (void*)(sVf + nb + dst[c]));
        }

        unsigned int pk[4][4][2];
#pragma unroll
        for (int mt = 0; mt < 4; ++mt)
#pragma unroll
            for (int g = 0; g < 4; ++g) {
                float p0 = fexp2(sacc[mt][4 * g + 0]);
                float p1 = fexp2(sacc[mt][4 * g + 1]);
                float p2 = fexp2(sacc[mt][4 * g + 2]);
                float p3 = fexp2(sacc[mt][4 * g + 3]);
                l2 += (f32x2){p0, p1};
                l2 += (f32x2){p2, p3};
                pk[mt][g][0] = __builtin_amdgcn_perm(
                    __builtin_bit_cast(unsigned int, p1),
                    __builtin_bit_cast(unsigned int, p0), 0x07060302u);
                pk[mt][g][1] = __builtin_amdgcn_perm(
                    __builtin_bit_cast(unsigned int, p3),
                    __builtin_bit_cast(unsigned int, p2), 0x07060302u);
            }

#pragma unroll
        for (int mt = 0; mt < 4; ++mt) {
#pragma unroll
            for (int ks2 = 0; ks2 < 2; ++ks2) {
                u32x4 bu;
                bu[0] = pk[mt][2 * ks2][0];
                bu[1] = pk[mt][2 * ks2][1];
                bu[2] = pk[mt][2 * ks2 + 1][0];
                bu[3] = pk[mt][2 * ks2 + 1][1];
                bf16x8 bfrag = __builtin_bit_cast(bf16x8, bu);
#pragma unroll
                for (int dt = 0; dt < 2; ++dt) {
                    bf16x8 vf = *(const bf16x8*)(sVf + va[mt & 1][ks2]
                                                 + (mt >> 1) * 64 + dt * 4096);
                    oacc[dt] = MFMA32(vf, bfrag, oacc[dt]);
                }
            }
        }

#pragma unroll
        for (int ks = 0; ks < 4; ++ks) ka[ks] ^= 8192;
        va[0][0] ^= 8192; va[0][1] ^= 8192; va[1][0] ^= 8192; va[1][1] ^= 8192;
        __syncthreads();
    }

    float l_run = l2[0] + l2[1];
    l_run += __shfl_xor(l_run, 32);
    const int b = bh >> 3, hh = bh & 7;
    float inv = 1.f / fmaxf(l_run, 1e-20f);
    unsigned short* obase = O + ((size_t)(b * 2048 + q0 + l31)) * 512 + hh * 64;
#pragma unroll
    for (int dt = 0; dt < 2; ++dt)
#pragma unroll
        for (int g = 0; g < 4; ++g) {
            int d = dt * 32 + 8 * g + 4 * h;
            unsigned int w0 = pk2(oacc[dt][4 * g + 0] * inv, oacc[dt][4 * g + 1] * inv);
            unsigned int w1 = pk2(oacc[dt][4 * g + 2] * inv, oacc[dt][4 * g + 3] * inv);
            uint2 w = {w0, w1};
            *(uint2*)(obase + d) = w;
        }
}

// ---------------------------------------------------------------------------
extern "C" void kernel_launch(void* const* d_in, const int* in_sizes, int n_in,
                              void* d_out, int out_size, void* d_ws, size_t ws_size,
                              hipStream_t stream)
{
    const float* x      = (const float*)d_in[0];  // [4,2048,512]
    const float* qkv_w  = (const float*)d_in[1];  // [1536,512]
    const float* qkv_b  = (const float*)d_in[2];  // [1536]
    const float* proj_w = (const float*)d_in[3];  // [512,512]
    const float* proj_b = (const float*)d_in[4];  // [512]

    const size_t PER = 4u * 8u * 2048u * 64u;     // 4,194,304 elems (8 MB bf16)
    unsigned short* q_ws  = (unsigned short*)d_ws;
    unsigned short* k_ws  = q_ws  + PER;
    unsigned short* vt_ws = k_ws  + PER;
    unsigned short* ao_ws = vt_ws + PER;
    unsigned short* wb2   = ao_ws + PER;          // proj_w bf16 (0.5 MB)

    // bf16 scratch inside d_out (16 MB; dead until final GEMM overwrites it)
    unsigned short* xb = (unsigned short*)d_out;          // 8 MB
    unsigned short* wb = xb + PER;                        // 1.5 MB

    // 0) bulk fp32->bf16 of x, qkv_w, proj_w (one launch)
    cvt_bf16<<<dim3(640), 256, 0, stream>>>(x, qkv_w, proj_w, xb, wb, wb2);
    // 1) QKV projection: M=8192, N=1536, K=512 (XCD-remapped)
    gemm_qkv<<<dim3(768), 256, 0, stream>>>(xb, wb, qkv_b, q_ws, k_ws, vt_ws, 512);
    // 2) Flash attention: 512 blocks, XCD-remapped (4 heads/XCD)
    attn_fused<<<dim3(512), 256, 0, stream>>>(q_ws, k_ws, vt_ws, ao_ws);
    // 3) Output projection: M=8192, N=512, K=512 (XCD-remapped)
    gemm_out<<<dim3(512), 256, 0, stream>>>(ao_ws, wb2, proj_b, (float*)d_out, 512, 512);
}